// Round 7
// baseline (270.468 us; speedup 1.0000x reference)
//
#include <hip/hip_runtime.h>

#define B 4
#define M 8192
#define NSTY 8192
#define KNB 8
#define F 288
#define NT (M + NSTY)   // 16384
#define BM (B * M)      // 32768
#define SEGL (M * F)    // 2359296 elements per convert segment

typedef __attribute__((ext_vector_type(8))) short short8;
typedef __attribute__((ext_vector_type(4))) float floatx4;
typedef __attribute__((ext_vector_type(2))) float floatx2;
typedef __attribute__((ext_vector_type(4))) unsigned int uintx4;

__device__ __forceinline__ float u2f(unsigned int u) {
    union { unsigned int u; float f; } c; c.u = u; return c.f;
}
__device__ __forceinline__ unsigned short f2b(float x) {
    union { float f; unsigned int u; } c; c.f = x;
    unsigned int r = c.u + 0x7FFFu + ((c.u >> 16) & 1u);
    return (unsigned short)(r >> 16);
}
__device__ __forceinline__ floatx2 bpair(unsigned int p) {
    floatx2 r;
    r.x = u2f(p << 16);
    r.y = u2f(p & 0xFFFF0000u);
    return r;
}
__device__ __forceinline__ void gload_lds16(const void* g, void* l) {
    __builtin_amdgcn_global_load_lds(
        (const __attribute__((address_space(1))) unsigned int*)g,
        (__attribute__((address_space(3))) unsigned int*)l, 16, 0, 0);
}

// ---------------- prep0: deg LDS-histogram (zero global atomics) + pack W ----------------
#define P0_DEG 4
#define P0_PKW 162   // 2*F*F / 1024
__global__ __launch_bounds__(1024) void prep0_kernel(
        const int* __restrict__ idx_k1, const int* __restrict__ idx_k2,
        int* __restrict__ deg,
        const float* __restrict__ W1, const float* __restrict__ W2,
        unsigned short* __restrict__ Wp1, unsigned short* __restrict__ Wp2) {
    int blk = blockIdx.x;
    int tid = threadIdx.x;
    if (blk < P0_DEG) {
        __shared__ int h[NT];   // 64 KB
        for (int i = tid; i < NT; i += 1024) h[i] = 0;
        __syncthreads();
        int b = blk;
        const int4* p2 = (const int4*)(idx_k2 + (size_t)b * M * KNB);
        const int4* p1 = (const int4*)(idx_k1 + (size_t)b * M * KNB);
        #pragma unroll 2
        for (int i = tid; i < (M * KNB) / 4; i += 1024) {
            int4 v = p2[i];
            atomicAdd(&h[v.x], 1); atomicAdd(&h[v.y], 1);
            atomicAdd(&h[v.z], 1); atomicAdd(&h[v.w], 1);
        }
        #pragma unroll 2
        for (int i = tid; i < (M * KNB) / 4; i += 1024) {
            int4 v = p1[i];
            atomicAdd(&h[M + v.x], 1); atomicAdd(&h[M + v.y], 1);
            atomicAdd(&h[M + v.z], 1); atomicAdd(&h[M + v.w], 1);
        }
        __syncthreads();
        int4* dst = (int4*)(deg + (size_t)b * NT);
        const int4* hs = (const int4*)h;
        for (int i = tid; i < NT / 4; i += 1024) dst[i] = hs[i];
    } else {
        int t = (blk - P0_DEG) * 1024 + tid;
        if (t >= 2 * F * F) return;
        int half = t >= F * F;
        int tt = t - half * F * F;
        int k = tt / F, n = tt - k * F;
        const float* W = half ? W2 : W1;
        unsigned short* Wp = half ? Wp2 : Wp1;
        Wp[((size_t)(k >> 3) * F + n) * 8 + (k & 7)] = f2b(W[tt]);
    }
}

// ---------------- prep1: f32->bf16 convert WITH prescale 0.25*dout(u)^-1/2 ----------------
// NT loads (read-once stream) + NT stores (consumed by other XCDs via L3; keep L2 clean).
#define P1_BLKS 576    // 8 segments x 72 blocks; 32768 elems/block
__global__ __launch_bounds__(1024) void prep1_kernel(
        const int* __restrict__ deg,
        const float* __restrict__ fc, const float* __restrict__ fs,
        unsigned short* __restrict__ fb) {
    int cb = blockIdx.x;
    int tid = threadIdx.x;
    int seg = cb / 72;                    // const divisor -> magic mul
    int bis = cb - seg * 72;
    int b = seg >> 1, sty = seg & 1;
    const float* src0 = (sty ? fs : fc) + (size_t)b * SEGL;
    unsigned short* dst0 = fb + (size_t)b * 2 * SEGL + (size_t)sty * SEGL;
    unsigned int e0 = (unsigned int)bis * 32768u + (unsigned int)tid * 8u;
    floatx4 x[8];
    #pragma unroll
    for (int j = 0; j < 4; ++j) {
        const floatx4* s = (const floatx4*)(src0 + e0 + j * 8192u);
        x[2 * j]     = __builtin_nontemporal_load(s);
        x[2 * j + 1] = __builtin_nontemporal_load(s + 1);
    }
    float w[4];
    #pragma unroll
    for (int j = 0; j < 4; ++j) {
        unsigned int row = (e0 + j * 8192u) / 288u;   // 8-elem chunk lies in one row (288%8==0)
        int dg = deg[b * NT + (sty ? M + (int)row : (int)row)];
        w[j] = 0.25f * rsqrtf((float)(dg < 1 ? 1 : dg));
    }
    #pragma unroll
    for (int j = 0; j < 4; ++j) {
        uintx4 o;
        o.x = (unsigned int)f2b(x[2*j].x*w[j])   | ((unsigned int)f2b(x[2*j].y*w[j])   << 16);
        o.y = (unsigned int)f2b(x[2*j].z*w[j])   | ((unsigned int)f2b(x[2*j].w*w[j])   << 16);
        o.z = (unsigned int)f2b(x[2*j+1].x*w[j]) | ((unsigned int)f2b(x[2*j+1].y*w[j]) << 16);
        o.w = (unsigned int)f2b(x[2*j+1].z*w[j]) | ((unsigned int)f2b(x[2*j+1].w*w[j]) << 16);
        __builtin_nontemporal_store(o, (uintx4*)(dst0 + e0 + j * 8192u));
    }
}

// ---------------- fused gather+GEMM: one 512-thread block = 64 output rows ----------------
// Gather phase: tables are PRESCALED -> plain sum. Software-pipelined 8-load batches
//   (vA/vB double-buffer). PHASE-MAJOR iteration: all content batches (half-table A,
//   4.7MB/XCD) before all style batches (half-table B), so each phase's XCD-wide
//   working set ~fits the 4MB L2. Needs acc[8] rows live (+64 VGPR, static idx).
// Output C stores are NONTEMPORAL: C lines are useless in this XCD's L2 and were
//   evicting the gather table (r4: FETCH 99MB vs 38MB table).
// LAYER==1: src=featb (NT rows/batch, prescaled), 16 edges; epilogue writes
//           h1p = relu(acc+b1) * 0.25*dout(row)^-1/2 (prescale for layer 2), bf16.
// LAYER==2: src=h1p (M rows/batch), 8 content edges (plain sum) + style const term
//           S*relu(b1); +b2, f32 out.
template<int LAYER>
__global__ __launch_bounds__(512, 1) void fused_kernel(
        const unsigned short* __restrict__ src_tbl,
        const int* __restrict__ idx_k1, const int* __restrict__ idx_k2,
        const int* __restrict__ deg,
        const float* __restrict__ bprev,
        const unsigned short* __restrict__ Wp,
        const float* __restrict__ bias,
        void* __restrict__ Cout) {
    const int NK = (LAYER == 1) ? 16 : 8;
    const int NB = NK / 8;                 // phases (2 or 1)
    const int TOT = 8 * NB;                // batches per wave, phase-major: t -> r=t&7, c=t>>3
    __shared__ __align__(16) unsigned short sA[64 * F];        // 36 KB gather output
    __shared__ __align__(16) unsigned short sB[2][4 * F * 8];  // 36 KB W double-buffer

    int tid = threadIdx.x;
    int wid = tid >> 6, lane = tid & 63;
    int blk = blockIdx.x;
    int rx = blk & 7;
    int b = rx >> 1;
    int sub = (blk >> 3) * 2 + (rx & 1);
    int rloc = sub * 64;
    int row0 = b * M + rloc;

    // prefetch W stage 0 under the whole gather phase
    if (tid < 128) {
        #pragma unroll
        for (int rr = 0; rr < 9; ++rr)
            gload_lds16(Wp + (rr * 128 + tid) * 8, &sB[0][(rr * 128 + tid) * 8]);
    }

    // ---- gather prologue: lane = i*16 + e covers 4 rows x 16 edges, two halves ----
    int i4 = lane >> 4, e = lane & 15;
    int rw0 = wid * 8;                     // this wave's first block-local row
    size_t eb0 = ((size_t)b * M + rloc + rw0 + i4) * KNB;
    size_t eb1 = eb0 + (size_t)4 * KNB;
    int u0, u1;
    if (e < 8) { u0 = idx_k2[eb0 + e];     u1 = idx_k2[eb1 + e]; }
    else       { u0 = M + idx_k1[eb0 + e - 8]; u1 = M + idx_k1[eb1 + e - 8]; }
    int uoff0 = u0 * (F * 2);              // byte offset of source row
    int uoff1 = u1 * (F * 2);

    float wst0 = 0.f, wst1 = 0.f;          // style-edge weights (LAYER 2 const term)
    if (LAYER == 2 && e >= 8) {
        int d0 = deg[b * NT + u0], d1 = deg[b * NT + u1];
        wst0 = 0.25f * rsqrtf((float)(d0 < 1 ? 1 : d0));
        wst1 = 0.25f * rsqrtf((float)(d1 < 1 ? 1 : d1));
    }

    float bb[8];
    if (LAYER == 2 && lane < 36) {
        float4 t0 = *(const float4*)(bprev + 8 * lane);
        float4 t1 = *(const float4*)(bprev + 8 * lane + 4);
        bb[0]=fmaxf(t0.x,0.f); bb[1]=fmaxf(t0.y,0.f); bb[2]=fmaxf(t0.z,0.f); bb[3]=fmaxf(t0.w,0.f);
        bb[4]=fmaxf(t1.x,0.f); bb[5]=fmaxf(t1.y,0.f); bb[6]=fmaxf(t1.z,0.f); bb[7]=fmaxf(t1.w,0.f);
    }

    const char* baseb = (const char*)(src_tbl + (size_t)b * (size_t)(LAYER == 1 ? NT : M) * F);
    unsigned int lane16 = (unsigned int)lane * 16u;
    floatx2 acc[8][4];                     // 8 rows live across phases (static idx only)

#define MKOFF(OFF, T) do {                                                   \
        int r_ = (T) & 7, c_ = (T) >> 3;                                     \
        int uo_ = (r_ & 4) ? uoff1 : uoff0;                                  \
        int sl_ = (r_ & 3) * 16 + c_ * 8;                                    \
        _Pragma("unroll")                                                    \
        for (int k_ = 0; k_ < 8; ++k_)                                       \
            OFF[k_] = (unsigned int)__shfl(uo_, sl_ + k_) + lane16;          \
    } while (0)

#define LD8(V, OFF) do { if (lane < 36) {                                    \
        _Pragma("unroll")                                                    \
        for (int k_ = 0; k_ < 8; ++k_)                                       \
            V[k_] = *(const uint4*)(baseb + OFF[k_]);                        \
    } } while (0)

#define CONSUME(V, T) do {                                                   \
        int r_ = (T) & 7, c_ = (T) >> 3;                                     \
        if (c_ == 0) {                                                       \
            if (LAYER == 2) {                                                \
                float ws_ = (r_ & 4) ? wst1 : wst0;                          \
                float S_ = 0.f;                                              \
                _Pragma("unroll")                                            \
                for (int j_ = 8; j_ < 16; ++j_)                              \
                    S_ += __shfl(ws_, (r_ & 3) * 16 + j_);                   \
                _Pragma("unroll")                                            \
                for (int j_ = 0; j_ < 4; ++j_) {                             \
                    acc[r_][j_].x = bb[2*j_] * S_;                           \
                    acc[r_][j_].y = bb[2*j_+1] * S_;                         \
                }                                                            \
            } else {                                                         \
                _Pragma("unroll")                                            \
                for (int j_ = 0; j_ < 4; ++j_)                               \
                    acc[r_][j_] = (floatx2){0.f, 0.f};                       \
            }                                                                \
        }                                                                    \
        _Pragma("unroll")                                                    \
        for (int k_ = 0; k_ < 8; ++k_) {                                     \
            acc[r_][0] += bpair(V[k_].x); acc[r_][1] += bpair(V[k_].y);      \
            acc[r_][2] += bpair(V[k_].z); acc[r_][3] += bpair(V[k_].w);      \
        }                                                                    \
        if (c_ == NB - 1 && lane < 36) {                                     \
            uint4 o_;                                                        \
            o_.x = (unsigned int)f2b(acc[r_][0].x) | ((unsigned int)f2b(acc[r_][0].y) << 16); \
            o_.y = (unsigned int)f2b(acc[r_][1].x) | ((unsigned int)f2b(acc[r_][1].y) << 16); \
            o_.z = (unsigned int)f2b(acc[r_][2].x) | ((unsigned int)f2b(acc[r_][2].y) << 16); \
            o_.w = (unsigned int)f2b(acc[r_][3].x) | ((unsigned int)f2b(acc[r_][3].y) << 16); \
            *(uint4*)&sA[(size_t)(rw0 + r_) * F + 8 * lane] = o_;            \
        }                                                                    \
    } while (0)

    // ---- software-pipelined gather: one 8-load batch always in flight ----
    unsigned int offA[8], offB[8];
    uint4 vA[8], vB[8];
    MKOFF(offA, 0); LD8(vA, offA);
    #pragma unroll
    for (int t = 0; t < TOT; t += 2) {
        if (t + 1 < TOT) { MKOFF(offB, t + 1); LD8(vB, offB); }
        CONSUME(vA, t);
        if (t + 2 < TOT) { MKOFF(offA, t + 2); LD8(vA, offA); }
        if (t + 1 < TOT) CONSUME(vB, t + 1);
    }
#undef MKOFF
#undef LD8
#undef CONSUME

    // ---- GEMM phase ----
    int wm = wid & 3, wn = wid >> 2;
    int quad = lane >> 4, r16 = lane & 15;

    floatx4 acc9[9];
    #pragma unroll
    for (int ct = 0; ct < 9; ++ct) acc9[ct] = (floatx4){0.f, 0.f, 0.f, 0.f};

    __syncthreads();   // sA complete + sB[0] staged

    for (int s = 0; s < 9; ++s) {
        if (s < 8 && tid < 128) {
            const unsigned short* srcw = Wp + (size_t)(s + 1) * 4 * F * 8;
            unsigned short* dstb = sB[(s + 1) & 1];
            #pragma unroll
            for (int rr = 0; rr < 9; ++rr)
                gload_lds16(srcw + (rr * 128 + tid) * 8, dstb + (rr * 128 + tid) * 8);
        }
        short8 a0 = *(const short8*)&sA[(wm * 16 + r16) * F + s * 32 + quad * 8];
        const unsigned short* bbp = &sB[s & 1][(quad * F + wn * 144 + r16) * 8];
        #pragma unroll
        for (int ct = 0; ct < 9; ++ct) {
            short8 bf = *(const short8*)(bbp + ct * 128);
            acc9[ct] = __builtin_amdgcn_mfma_f32_16x16x32_bf16(a0, bf, acc9[ct], 0, 0, 0);
        }
        __syncthreads();
    }

    // ---- epilogue (NONTEMPORAL C stores: keep gather table resident in L2) ----
    if (LAYER == 1) {
        // prescale rows for layer 2: h1p = relu(acc+b1) * 0.25*dout(row)^-1/2
        int nid = rloc + wm * 16 + quad * 4;          // local content node id (mult of 4)
        int4 dv = *(const int4*)&deg[b * NT + nid];
        float w4[4];
        w4[0] = 0.25f * rsqrtf((float)(dv.x < 1 ? 1 : dv.x));
        w4[1] = 0.25f * rsqrtf((float)(dv.y < 1 ? 1 : dv.y));
        w4[2] = 0.25f * rsqrtf((float)(dv.z < 1 ? 1 : dv.z));
        w4[3] = 0.25f * rsqrtf((float)(dv.w < 1 ? 1 : dv.w));
        #pragma unroll
        for (int ct = 0; ct < 9; ++ct) {
            int col = wn * 144 + ct * 16 + r16;
            float bc = bias[col];
            #pragma unroll
            for (int rg = 0; rg < 4; ++rg) {
                float v = fmaxf(acc9[ct][rg] + bc, 0.f) * w4[rg];
                int grow = row0 + wm * 16 + quad * 4 + rg;
                __builtin_nontemporal_store(f2b(v),
                    (unsigned short*)Cout + (size_t)grow * F + col);
            }
        }
    } else {
        #pragma unroll
        for (int ct = 0; ct < 9; ++ct) {
            int col = wn * 144 + ct * 16 + r16;
            float bc = bias[col];
            #pragma unroll
            for (int rg = 0; rg < 4; ++rg) {
                float v = acc9[ct][rg] + bc;
                int grow = row0 + wm * 16 + quad * 4 + rg;
                __builtin_nontemporal_store(v, (float*)Cout + (size_t)grow * F + col);
            }
        }
    }
}

extern "C" void kernel_launch(void* const* d_in, const int* in_sizes, int n_in,
                              void* d_out, int out_size, void* d_ws, size_t ws_size,
                              hipStream_t stream) {
    const float* feat_c = (const float*)d_in[0];
    const float* feat_s = (const float*)d_in[1];
    const int*   idx_k1 = (const int*)d_in[2];
    const int*   idx_k2 = (const int*)d_in[3];
    const float* W1     = (const float*)d_in[4];
    const float* b1     = (const float*)d_in[5];
    const float* W2     = (const float*)d_in[6];
    const float* b2     = (const float*)d_in[7];

    char* ws = (char*)d_ws;
    int*            deg  = (int*)ws;                                    // 256 KB
    unsigned short* Wp1  = (unsigned short*)(ws + 262144);
    unsigned short* Wp2  = (unsigned short*)(ws + 262144 + 165888);
    unsigned short* h1b  = (unsigned short*)(ws + 262144 + 2 * 165888); // 18.9 MB (prescaled h1)

    unsigned short* featb = (unsigned short*)d_out;  // 37.75 MB prescaled bf16 table
    float*          out   = (float*)d_out;           // overwrites featb (dead after fused1)

    prep0_kernel<<<P0_DEG + P0_PKW, 1024, 0, stream>>>(
        idx_k1, idx_k2, deg, W1, W2, Wp1, Wp2);

    prep1_kernel<<<P1_BLKS, 1024, 0, stream>>>(deg, feat_c, feat_s, featb);

    fused_kernel<1><<<BM / 64, 512, 0, stream>>>(
        featb, idx_k1, idx_k2, deg, b1, Wp1, b1, (void*)h1b);

    fused_kernel<2><<<BM / 64, 512, 0, stream>>>(
        h1b, idx_k1, idx_k2, deg, b1, Wp2, b2, (void*)out);
}

// Round 8
// 219.559 us; speedup vs baseline: 1.2319x; 1.2319x over previous
//
#include <hip/hip_runtime.h>

#define B 4
#define M 8192
#define NSTY 8192
#define KNB 8
#define F 288
#define NT (M + NSTY)   // 16384
#define BM (B * M)      // 32768
#define SEGL (M * F)    // 2359296 elements per convert segment

typedef __attribute__((ext_vector_type(8))) short short8;
typedef __attribute__((ext_vector_type(4))) float floatx4;
typedef __attribute__((ext_vector_type(2))) float floatx2;
typedef __attribute__((ext_vector_type(4))) unsigned int uintx4;

__device__ __forceinline__ float u2f(unsigned int u) {
    union { unsigned int u; float f; } c; c.u = u; return c.f;
}
__device__ __forceinline__ unsigned short f2b(float x) {
    union { float f; unsigned int u; } c; c.f = x;
    unsigned int r = c.u + 0x7FFFu + ((c.u >> 16) & 1u);
    return (unsigned short)(r >> 16);
}
__device__ __forceinline__ floatx2 bpair(unsigned int p) {
    floatx2 r;
    r.x = u2f(p << 16);
    r.y = u2f(p & 0xFFFF0000u);
    return r;
}
__device__ __forceinline__ void gload_lds16(const void* g, void* l) {
    __builtin_amdgcn_global_load_lds(
        (const __attribute__((address_space(1))) unsigned int*)g,
        (__attribute__((address_space(3))) unsigned int*)l, 16, 0, 0);
}

// ---------------- prep0: deg LDS-histogram (zero global atomics) + pack W ----------------
#define P0_DEG 4
#define P0_PKW 162   // 2*F*F / 1024
__global__ __launch_bounds__(1024) void prep0_kernel(
        const int* __restrict__ idx_k1, const int* __restrict__ idx_k2,
        int* __restrict__ deg,
        const float* __restrict__ W1, const float* __restrict__ W2,
        unsigned short* __restrict__ Wp1, unsigned short* __restrict__ Wp2) {
    int blk = blockIdx.x;
    int tid = threadIdx.x;
    if (blk < P0_DEG) {
        __shared__ int h[NT];   // 64 KB
        for (int i = tid; i < NT; i += 1024) h[i] = 0;
        __syncthreads();
        int b = blk;
        const int4* p2 = (const int4*)(idx_k2 + (size_t)b * M * KNB);
        const int4* p1 = (const int4*)(idx_k1 + (size_t)b * M * KNB);
        #pragma unroll 2
        for (int i = tid; i < (M * KNB) / 4; i += 1024) {
            int4 v = p2[i];
            atomicAdd(&h[v.x], 1); atomicAdd(&h[v.y], 1);
            atomicAdd(&h[v.z], 1); atomicAdd(&h[v.w], 1);
        }
        #pragma unroll 2
        for (int i = tid; i < (M * KNB) / 4; i += 1024) {
            int4 v = p1[i];
            atomicAdd(&h[M + v.x], 1); atomicAdd(&h[M + v.y], 1);
            atomicAdd(&h[M + v.z], 1); atomicAdd(&h[M + v.w], 1);
        }
        __syncthreads();
        int4* dst = (int4*)(deg + (size_t)b * NT);
        const int4* hs = (const int4*)h;
        for (int i = tid; i < NT / 4; i += 1024) dst[i] = hs[i];
    } else {
        int t = (blk - P0_DEG) * 1024 + tid;
        if (t >= 2 * F * F) return;
        int half = t >= F * F;
        int tt = t - half * F * F;
        int k = tt / F, n = tt - k * F;
        const float* W = half ? W2 : W1;
        unsigned short* Wp = half ? Wp2 : Wp1;
        Wp[((size_t)(k >> 3) * F + n) * 8 + (k & 7)] = f2b(W[tt]);
    }
}

// ---------------- prep1: f32->bf16 convert WITH prescale 0.25*dout(u)^-1/2 ----------------
// NT loads (read-once stream) + NT stores (consumer is on other XCDs; keep L2 clean).
#define P1_BLKS 576    // 8 segments x 72 blocks; 32768 elems/block
__global__ __launch_bounds__(1024) void prep1_kernel(
        const int* __restrict__ deg,
        const float* __restrict__ fc, const float* __restrict__ fs,
        unsigned short* __restrict__ fb) {
    int cb = blockIdx.x;
    int tid = threadIdx.x;
    int seg = cb / 72;                    // const divisor -> magic mul
    int bis = cb - seg * 72;
    int b = seg >> 1, sty = seg & 1;
    const float* src0 = (sty ? fs : fc) + (size_t)b * SEGL;
    unsigned short* dst0 = fb + (size_t)b * 2 * SEGL + (size_t)sty * SEGL;
    unsigned int e0 = (unsigned int)bis * 32768u + (unsigned int)tid * 8u;
    floatx4 x[8];
    #pragma unroll
    for (int j = 0; j < 4; ++j) {
        const floatx4* s = (const floatx4*)(src0 + e0 + j * 8192u);
        x[2 * j]     = __builtin_nontemporal_load(s);
        x[2 * j + 1] = __builtin_nontemporal_load(s + 1);
    }
    float w[4];
    #pragma unroll
    for (int j = 0; j < 4; ++j) {
        unsigned int row = (e0 + j * 8192u) / 288u;   // 8-elem chunk lies in one row (288%8==0)
        int dg = deg[b * NT + (sty ? M + (int)row : (int)row)];
        w[j] = 0.25f * rsqrtf((float)(dg < 1 ? 1 : dg));
    }
    #pragma unroll
    for (int j = 0; j < 4; ++j) {
        uintx4 o;
        o.x = (unsigned int)f2b(x[2*j].x*w[j])   | ((unsigned int)f2b(x[2*j].y*w[j])   << 16);
        o.y = (unsigned int)f2b(x[2*j].z*w[j])   | ((unsigned int)f2b(x[2*j].w*w[j])   << 16);
        o.z = (unsigned int)f2b(x[2*j+1].x*w[j]) | ((unsigned int)f2b(x[2*j+1].y*w[j]) << 16);
        o.w = (unsigned int)f2b(x[2*j+1].z*w[j]) | ((unsigned int)f2b(x[2*j+1].w*w[j]) << 16);
        __builtin_nontemporal_store(o, (uintx4*)(dst0 + e0 + j * 8192u));
    }
}

// ---------------- fused gather+GEMM: one 512-thread block = 64 output rows ----------------
// ROUND-5 STRUCTURE (best measured, 209.6us): row-major pipelined gather, acc[4] only.
// Round 7 lesson: this loop has ~0 VGPR headroom at the compiler's 128-VGPR choice;
// acc[8][4] phase-major (+56 VGPR) spilled to scratch (WRITE 151MB, 128us). Do not
// add live state to the gather loop.
// This round's single change vs round 5: NONTEMPORAL epilogue C-stores (zero register
// cost) -> C lines stop evicting the gather table from L2 (r4: FETCH 99MB vs 38MB table).
template<int LAYER>
__global__ __launch_bounds__(512, 1) void fused_kernel(
        const unsigned short* __restrict__ src_tbl,
        const int* __restrict__ idx_k1, const int* __restrict__ idx_k2,
        const int* __restrict__ deg,
        const float* __restrict__ bprev,
        const unsigned short* __restrict__ Wp,
        const float* __restrict__ bias,
        void* __restrict__ Cout) {
    const int NK = (LAYER == 1) ? 16 : 8;
    const int NB = NK / 8;                 // batches per row (2 or 1)
    const int TOT = 8 * NB;                // batches per wave (16 or 8), always even
    __shared__ __align__(16) unsigned short sA[64 * F];        // 36 KB gather output
    __shared__ __align__(16) unsigned short sB[2][4 * F * 8];  // 36 KB W double-buffer

    int tid = threadIdx.x;
    int wid = tid >> 6, lane = tid & 63;
    int blk = blockIdx.x;
    int rx = blk & 7;
    int b = rx >> 1;
    int sub = (blk >> 3) * 2 + (rx & 1);
    int rloc = sub * 64;
    int row0 = b * M + rloc;

    // prefetch W stage 0 under the whole gather phase
    if (tid < 128) {
        #pragma unroll
        for (int rr = 0; rr < 9; ++rr)
            gload_lds16(Wp + (rr * 128 + tid) * 8, &sB[0][(rr * 128 + tid) * 8]);
    }

    // ---- gather prologue: lane = i*16 + e covers 4 rows x 16 edges, two halves ----
    int i4 = lane >> 4, e = lane & 15;
    int rw0 = wid * 8;                     // this wave's first block-local row
    size_t eb0 = ((size_t)b * M + rloc + rw0 + i4) * KNB;
    size_t eb1 = eb0 + (size_t)4 * KNB;
    int u0, u1;
    if (e < 8) { u0 = idx_k2[eb0 + e];     u1 = idx_k2[eb1 + e]; }
    else       { u0 = M + idx_k1[eb0 + e - 8]; u1 = M + idx_k1[eb1 + e - 8]; }
    int uoff0 = u0 * (F * 2);              // byte offset of source row
    int uoff1 = u1 * (F * 2);

    float wst0 = 0.f, wst1 = 0.f;          // style-edge weights (LAYER 2 const term)
    if (LAYER == 2 && e >= 8) {
        int d0 = deg[b * NT + u0], d1 = deg[b * NT + u1];
        wst0 = 0.25f * rsqrtf((float)(d0 < 1 ? 1 : d0));
        wst1 = 0.25f * rsqrtf((float)(d1 < 1 ? 1 : d1));
    }

    float bb[8];
    if (LAYER == 2 && lane < 36) {
        float4 t0 = *(const float4*)(bprev + 8 * lane);
        float4 t1 = *(const float4*)(bprev + 8 * lane + 4);
        bb[0]=fmaxf(t0.x,0.f); bb[1]=fmaxf(t0.y,0.f); bb[2]=fmaxf(t0.z,0.f); bb[3]=fmaxf(t0.w,0.f);
        bb[4]=fmaxf(t1.x,0.f); bb[5]=fmaxf(t1.y,0.f); bb[6]=fmaxf(t1.z,0.f); bb[7]=fmaxf(t1.w,0.f);
    }

    const char* baseb = (const char*)(src_tbl + (size_t)b * (size_t)(LAYER == 1 ? NT : M) * F);
    unsigned int lane16 = (unsigned int)lane * 16u;
    floatx2 acc[4];

#define MKOFF(OFF, T) do {                                                   \
        int r_ = (T) / NB, c_ = (T) % NB;                                    \
        int uo_ = (r_ & 4) ? uoff1 : uoff0;                                  \
        int sl_ = (r_ & 3) * 16 + c_ * 8;                                    \
        _Pragma("unroll")                                                    \
        for (int k_ = 0; k_ < 8; ++k_)                                       \
            OFF[k_] = (unsigned int)__shfl(uo_, sl_ + k_) + lane16;          \
    } while (0)

#define LD8(V, OFF) do { if (lane < 36) {                                    \
        _Pragma("unroll")                                                    \
        for (int k_ = 0; k_ < 8; ++k_)                                       \
            V[k_] = *(const uint4*)(baseb + OFF[k_]);                        \
    } } while (0)

#define CONSUME(V, T) do {                                                   \
        int r_ = (T) / NB, c_ = (T) % NB;                                    \
        if (c_ == 0) {                                                       \
            if (LAYER == 2) {                                                \
                float ws_ = (r_ & 4) ? wst1 : wst0;                          \
                float S_ = 0.f;                                              \
                _Pragma("unroll")                                            \
                for (int j_ = 8; j_ < 16; ++j_)                              \
                    S_ += __shfl(ws_, (r_ & 3) * 16 + j_);                   \
                _Pragma("unroll")                                            \
                for (int j_ = 0; j_ < 4; ++j_) {                             \
                    acc[j_].x = bb[2*j_] * S_; acc[j_].y = bb[2*j_+1] * S_;  \
                }                                                            \
            } else {                                                         \
                _Pragma("unroll")                                            \
                for (int j_ = 0; j_ < 4; ++j_) acc[j_] = (floatx2){0.f,0.f}; \
            }                                                                \
        }                                                                    \
        _Pragma("unroll")                                                    \
        for (int k_ = 0; k_ < 8; ++k_) {                                     \
            acc[0] += bpair(V[k_].x); acc[1] += bpair(V[k_].y);              \
            acc[2] += bpair(V[k_].z); acc[3] += bpair(V[k_].w);              \
        }                                                                    \
        if (c_ == NB - 1 && lane < 36) {                                     \
            uint4 o_;                                                        \
            o_.x = (unsigned int)f2b(acc[0].x) | ((unsigned int)f2b(acc[0].y) << 16); \
            o_.y = (unsigned int)f2b(acc[1].x) | ((unsigned int)f2b(acc[1].y) << 16); \
            o_.z = (unsigned int)f2b(acc[2].x) | ((unsigned int)f2b(acc[2].y) << 16); \
            o_.w = (unsigned int)f2b(acc[3].x) | ((unsigned int)f2b(acc[3].y) << 16); \
            *(uint4*)&sA[(size_t)(rw0 + r_) * F + 8 * lane] = o_;            \
        }                                                                    \
    } while (0)

    // ---- software-pipelined gather: one 8-load batch always in flight ----
    unsigned int offA[8], offB[8];
    uint4 vA[8], vB[8];
    MKOFF(offA, 0); LD8(vA, offA);
    #pragma unroll
    for (int t = 0; t < TOT; t += 2) {
        if (t + 1 < TOT) { MKOFF(offB, t + 1); LD8(vB, offB); }
        CONSUME(vA, t);
        if (t + 2 < TOT) { MKOFF(offA, t + 2); LD8(vA, offA); }
        if (t + 1 < TOT) CONSUME(vB, t + 1);
    }
#undef MKOFF
#undef LD8
#undef CONSUME

    // ---- GEMM phase ----
    int wm = wid & 3, wn = wid >> 2;
    int quad = lane >> 4, r16 = lane & 15;

    floatx4 acc9[9];
    #pragma unroll
    for (int ct = 0; ct < 9; ++ct) acc9[ct] = (floatx4){0.f, 0.f, 0.f, 0.f};

    __syncthreads();   // sA complete + sB[0] staged

    for (int s = 0; s < 9; ++s) {
        if (s < 8 && tid < 128) {
            const unsigned short* srcw = Wp + (size_t)(s + 1) * 4 * F * 8;
            unsigned short* dstb = sB[(s + 1) & 1];
            #pragma unroll
            for (int rr = 0; rr < 9; ++rr)
                gload_lds16(srcw + (rr * 128 + tid) * 8, dstb + (rr * 128 + tid) * 8);
        }
        short8 a0 = *(const short8*)&sA[(wm * 16 + r16) * F + s * 32 + quad * 8];
        const unsigned short* bbp = &sB[s & 1][(quad * F + wn * 144 + r16) * 8];
        #pragma unroll
        for (int ct = 0; ct < 9; ++ct) {
            short8 bf = *(const short8*)(bbp + ct * 128);
            acc9[ct] = __builtin_amdgcn_mfma_f32_16x16x32_bf16(a0, bf, acc9[ct], 0, 0, 0);
        }
        __syncthreads();
    }

    // ---- epilogue (NONTEMPORAL C stores: keep gather table resident in L2) ----
    if (LAYER == 1) {
        // prescale rows for layer 2: h1p = relu(acc+b1) * 0.25*dout(row)^-1/2
        int nid = rloc + wm * 16 + quad * 4;          // local content node id (mult of 4)
        int4 dv = *(const int4*)&deg[b * NT + nid];
        float w4[4];
        w4[0] = 0.25f * rsqrtf((float)(dv.x < 1 ? 1 : dv.x));
        w4[1] = 0.25f * rsqrtf((float)(dv.y < 1 ? 1 : dv.y));
        w4[2] = 0.25f * rsqrtf((float)(dv.z < 1 ? 1 : dv.z));
        w4[3] = 0.25f * rsqrtf((float)(dv.w < 1 ? 1 : dv.w));
        #pragma unroll
        for (int ct = 0; ct < 9; ++ct) {
            int col = wn * 144 + ct * 16 + r16;
            float bc = bias[col];
            #pragma unroll
            for (int rg = 0; rg < 4; ++rg) {
                float v = fmaxf(acc9[ct][rg] + bc, 0.f) * w4[rg];
                int grow = row0 + wm * 16 + quad * 4 + rg;
                __builtin_nontemporal_store(f2b(v),
                    (unsigned short*)Cout + (size_t)grow * F + col);
            }
        }
    } else {
        #pragma unroll
        for (int ct = 0; ct < 9; ++ct) {
            int col = wn * 144 + ct * 16 + r16;
            float bc = bias[col];
            #pragma unroll
            for (int rg = 0; rg < 4; ++rg) {
                float v = acc9[ct][rg] + bc;
                int grow = row0 + wm * 16 + quad * 4 + rg;
                __builtin_nontemporal_store(v, (float*)Cout + (size_t)grow * F + col);
            }
        }
    }
}

extern "C" void kernel_launch(void* const* d_in, const int* in_sizes, int n_in,
                              void* d_out, int out_size, void* d_ws, size_t ws_size,
                              hipStream_t stream) {
    const float* feat_c = (const float*)d_in[0];
    const float* feat_s = (const float*)d_in[1];
    const int*   idx_k1 = (const int*)d_in[2];
    const int*   idx_k2 = (const int*)d_in[3];
    const float* W1     = (const float*)d_in[4];
    const float* b1     = (const float*)d_in[5];
    const float* W2     = (const float*)d_in[6];
    const float* b2     = (const float*)d_in[7];

    char* ws = (char*)d_ws;
    int*            deg  = (int*)ws;                                    // 256 KB
    unsigned short* Wp1  = (unsigned short*)(ws + 262144);
    unsigned short* Wp2  = (unsigned short*)(ws + 262144 + 165888);
    unsigned short* h1b  = (unsigned short*)(ws + 262144 + 2 * 165888); // 18.9 MB (prescaled h1)

    unsigned short* featb = (unsigned short*)d_out;  // 37.75 MB prescaled bf16 table
    float*          out   = (float*)d_out;           // overwrites featb (dead after fused1)

    prep0_kernel<<<P0_DEG + P0_PKW, 1024, 0, stream>>>(
        idx_k1, idx_k2, deg, W1, W2, Wp1, Wp2);

    prep1_kernel<<<P1_BLKS, 1024, 0, stream>>>(deg, feat_c, feat_s, featb);

    fused_kernel<1><<<BM / 64, 512, 0, stream>>>(
        featb, idx_k1, idx_k2, deg, b1, Wp1, b1, (void*)h1b);

    fused_kernel<2><<<BM / 64, 512, 0, stream>>>(
        h1b, idx_k1, idx_k2, deg, b1, Wp2, b2, (void*)out);
}

// Round 9
// 205.326 us; speedup vs baseline: 1.3173x; 1.0693x over previous
//
#include <hip/hip_runtime.h>

#define B 4
#define M 8192
#define NSTY 8192
#define KNB 8
#define F 288
#define NT (M + NSTY)   // 16384
#define BM (B * M)      // 32768
#define SEGL (M * F)    // 2359296 elements per convert segment

typedef __attribute__((ext_vector_type(8))) short short8;
typedef __attribute__((ext_vector_type(4))) float floatx4;
typedef __attribute__((ext_vector_type(2))) float floatx2;

__device__ __forceinline__ float u2f(unsigned int u) {
    union { unsigned int u; float f; } c; c.u = u; return c.f;
}
__device__ __forceinline__ unsigned short f2b(float x) {
    union { float f; unsigned int u; } c; c.f = x;
    unsigned int r = c.u + 0x7FFFu + ((c.u >> 16) & 1u);
    return (unsigned short)(r >> 16);
}
__device__ __forceinline__ floatx2 bpair(unsigned int p) {
    floatx2 r;
    r.x = u2f(p << 16);
    r.y = u2f(p & 0xFFFF0000u);
    return r;
}
__device__ __forceinline__ void gload_lds16(const void* g, void* l) {
    __builtin_amdgcn_global_load_lds(
        (const __attribute__((address_space(1))) unsigned int*)g,
        (__attribute__((address_space(3))) unsigned int*)l, 16, 0, 0);
}

// ---------------- prep0: deg LDS-histograms + pack W ----------------
// 8 deg blocks (batch x {idx_k2->content bins, idx_k1->style bins}): disjoint
// 32KB half-range histograms, zero cross-block atomics, 2x the CUs vs r5's 4-block
// version (which serialized a 2MB scan + 256K LDS atomics per block at the
// pipeline head).
#define P0_DEG 8
#define P0_PKW 162   // 2*F*F / 1024
__global__ __launch_bounds__(1024) void prep0_kernel(
        const int* __restrict__ idx_k1, const int* __restrict__ idx_k2,
        int* __restrict__ deg,
        const float* __restrict__ W1, const float* __restrict__ W2,
        unsigned short* __restrict__ Wp1, unsigned short* __restrict__ Wp2) {
    int blk = blockIdx.x;
    int tid = threadIdx.x;
    if (blk < P0_DEG) {
        __shared__ int h[M];   // 32 KB half-range histogram
        int b = blk >> 1, half = blk & 1;
        for (int i = tid; i < M; i += 1024) h[i] = 0;
        __syncthreads();
        const int4* p = (const int4*)((half ? idx_k1 : idx_k2) + (size_t)b * M * KNB);
        #pragma unroll 4
        for (int i = tid; i < (M * KNB) / 4; i += 1024) {
            int4 v = p[i];
            atomicAdd(&h[v.x], 1); atomicAdd(&h[v.y], 1);
            atomicAdd(&h[v.z], 1); atomicAdd(&h[v.w], 1);
        }
        __syncthreads();
        int4* dst = (int4*)(deg + (size_t)b * NT + half * M);
        const int4* hs = (const int4*)h;
        for (int i = tid; i < M / 4; i += 1024) dst[i] = hs[i];
    } else {
        int t = (blk - P0_DEG) * 1024 + tid;
        if (t >= 2 * F * F) return;
        int half = t >= F * F;
        int tt = t - half * F * F;
        int k = tt / F, n = tt - k * F;
        const float* W = half ? W2 : W1;
        unsigned short* Wp = half ? Wp2 : Wp1;
        Wp[((size_t)(k >> 3) * F + n) * 8 + (k & 7)] = f2b(W[tt]);
    }
}

// ---------------- prep1: f32->bf16 convert WITH prescale 0.25*dout(u)^-1/2 ----------------
// (edge weight dout^-1/2 is a property of the SOURCE row; din==16 const -> fold 0.25 too.
//  This turns all gathers into plain sums.)
// NOTE: r8 lesson — NO nontemporal builtins anywhere: they flipped codegen to a
// 60-VGPR allocation in the fused kernel (scratch spill, +10us total). Plain loads.
#define P1_BLKS 576    // 8 segments x 72 blocks; 32768 elems/block
__global__ __launch_bounds__(1024) void prep1_kernel(
        const int* __restrict__ deg,
        const float* __restrict__ fc, const float* __restrict__ fs,
        unsigned short* __restrict__ fb) {
    int cb = blockIdx.x;
    int tid = threadIdx.x;
    int seg = cb / 72;                    // const divisor -> magic mul
    int bis = cb - seg * 72;
    int b = seg >> 1, sty = seg & 1;
    const float* src0 = (sty ? fs : fc) + (size_t)b * SEGL;
    unsigned short* dst0 = fb + (size_t)b * 2 * SEGL + (size_t)sty * SEGL;
    unsigned int e0 = (unsigned int)bis * 32768u + (unsigned int)tid * 8u;
    float4 x[8];
    #pragma unroll
    for (int j = 0; j < 4; ++j) {
        const float* s = src0 + e0 + j * 8192u;
        x[2 * j]     = *(const float4*)s;
        x[2 * j + 1] = *(const float4*)(s + 4);
    }
    float w[4];
    #pragma unroll
    for (int j = 0; j < 4; ++j) {
        unsigned int row = (e0 + j * 8192u) / 288u;   // 8-elem chunk lies in one row (288%8==0)
        int dg = deg[b * NT + (sty ? M + (int)row : (int)row)];
        w[j] = 0.25f * rsqrtf((float)(dg < 1 ? 1 : dg));
    }
    #pragma unroll
    for (int j = 0; j < 4; ++j) {
        uint4 o;
        o.x = (unsigned int)f2b(x[2*j].x*w[j])   | ((unsigned int)f2b(x[2*j].y*w[j])   << 16);
        o.y = (unsigned int)f2b(x[2*j].z*w[j])   | ((unsigned int)f2b(x[2*j].w*w[j])   << 16);
        o.z = (unsigned int)f2b(x[2*j+1].x*w[j]) | ((unsigned int)f2b(x[2*j+1].y*w[j]) << 16);
        o.w = (unsigned int)f2b(x[2*j+1].z*w[j]) | ((unsigned int)f2b(x[2*j+1].w*w[j]) << 16);
        *(uint4*)(dst0 + e0 + j * 8192u) = o;
    }
}

// ---------------- fused gather+GEMM: one 512-thread block = 64 output rows ----------------
// ROUND-5 STRUCTURE EXACTLY (best measured, 209.6us): row-major pipelined gather,
// acc[4] only, plain stores. VGPR budget is a hard wall: >128 VGPR drops occupancy
// 16->8 waves/CU (m69 step) or spills (r7: acc[8][4] -> 151MB scratch writes).
// Do not add live state to the gather loop.
template<int LAYER>
__global__ __launch_bounds__(512, 1) void fused_kernel(
        const unsigned short* __restrict__ src_tbl,
        const int* __restrict__ idx_k1, const int* __restrict__ idx_k2,
        const int* __restrict__ deg,
        const float* __restrict__ bprev,
        const unsigned short* __restrict__ Wp,
        const float* __restrict__ bias,
        void* __restrict__ Cout) {
    const int NK = (LAYER == 1) ? 16 : 8;
    const int NB = NK / 8;                 // batches per row (2 or 1)
    const int TOT = 8 * NB;                // batches per wave (16 or 8), always even
    __shared__ __align__(16) unsigned short sA[64 * F];        // 36 KB gather output
    __shared__ __align__(16) unsigned short sB[2][4 * F * 8];  // 36 KB W double-buffer

    int tid = threadIdx.x;
    int wid = tid >> 6, lane = tid & 63;
    int blk = blockIdx.x;
    int rx = blk & 7;
    int b = rx >> 1;
    int sub = (blk >> 3) * 2 + (rx & 1);
    int rloc = sub * 64;
    int row0 = b * M + rloc;

    // prefetch W stage 0 under the whole gather phase
    if (tid < 128) {
        #pragma unroll
        for (int rr = 0; rr < 9; ++rr)
            gload_lds16(Wp + (rr * 128 + tid) * 8, &sB[0][(rr * 128 + tid) * 8]);
    }

    // ---- gather prologue: lane = i*16 + e covers 4 rows x 16 edges, two halves ----
    int i4 = lane >> 4, e = lane & 15;
    int rw0 = wid * 8;                     // this wave's first block-local row
    size_t eb0 = ((size_t)b * M + rloc + rw0 + i4) * KNB;
    size_t eb1 = eb0 + (size_t)4 * KNB;
    int u0, u1;
    if (e < 8) { u0 = idx_k2[eb0 + e];     u1 = idx_k2[eb1 + e]; }
    else       { u0 = M + idx_k1[eb0 + e - 8]; u1 = M + idx_k1[eb1 + e - 8]; }
    int uoff0 = u0 * (F * 2);              // byte offset of source row
    int uoff1 = u1 * (F * 2);

    float wst0 = 0.f, wst1 = 0.f;          // style-edge weights (LAYER 2 const term)
    if (LAYER == 2 && e >= 8) {
        int d0 = deg[b * NT + u0], d1 = deg[b * NT + u1];
        wst0 = 0.25f * rsqrtf((float)(d0 < 1 ? 1 : d0));
        wst1 = 0.25f * rsqrtf((float)(d1 < 1 ? 1 : d1));
    }

    float bb[8];
    if (LAYER == 2 && lane < 36) {
        float4 t0 = *(const float4*)(bprev + 8 * lane);
        float4 t1 = *(const float4*)(bprev + 8 * lane + 4);
        bb[0]=fmaxf(t0.x,0.f); bb[1]=fmaxf(t0.y,0.f); bb[2]=fmaxf(t0.z,0.f); bb[3]=fmaxf(t0.w,0.f);
        bb[4]=fmaxf(t1.x,0.f); bb[5]=fmaxf(t1.y,0.f); bb[6]=fmaxf(t1.z,0.f); bb[7]=fmaxf(t1.w,0.f);
    }

    const char* baseb = (const char*)(src_tbl + (size_t)b * (size_t)(LAYER == 1 ? NT : M) * F);
    unsigned int lane16 = (unsigned int)lane * 16u;
    floatx2 acc[4];

#define MKOFF(OFF, T) do {                                                   \
        int r_ = (T) / NB, c_ = (T) % NB;                                    \
        int uo_ = (r_ & 4) ? uoff1 : uoff0;                                  \
        int sl_ = (r_ & 3) * 16 + c_ * 8;                                    \
        _Pragma("unroll")                                                    \
        for (int k_ = 0; k_ < 8; ++k_)                                       \
            OFF[k_] = (unsigned int)__shfl(uo_, sl_ + k_) + lane16;          \
    } while (0)

#define LD8(V, OFF) do { if (lane < 36) {                                    \
        _Pragma("unroll")                                                    \
        for (int k_ = 0; k_ < 8; ++k_)                                       \
            V[k_] = *(const uint4*)(baseb + OFF[k_]);                        \
    } } while (0)

#define CONSUME(V, T) do {                                                   \
        int r_ = (T) / NB, c_ = (T) % NB;                                    \
        if (c_ == 0) {                                                       \
            if (LAYER == 2) {                                                \
                float ws_ = (r_ & 4) ? wst1 : wst0;                          \
                float S_ = 0.f;                                              \
                _Pragma("unroll")                                            \
                for (int j_ = 8; j_ < 16; ++j_)                              \
                    S_ += __shfl(ws_, (r_ & 3) * 16 + j_);                   \
                _Pragma("unroll")                                            \
                for (int j_ = 0; j_ < 4; ++j_) {                             \
                    acc[j_].x = bb[2*j_] * S_; acc[j_].y = bb[2*j_+1] * S_;  \
                }                                                            \
            } else {                                                         \
                _Pragma("unroll")                                            \
                for (int j_ = 0; j_ < 4; ++j_) acc[j_] = (floatx2){0.f,0.f}; \
            }                                                                \
        }                                                                    \
        _Pragma("unroll")                                                    \
        for (int k_ = 0; k_ < 8; ++k_) {                                     \
            acc[0] += bpair(V[k_].x); acc[1] += bpair(V[k_].y);              \
            acc[2] += bpair(V[k_].z); acc[3] += bpair(V[k_].w);              \
        }                                                                    \
        if (c_ == NB - 1 && lane < 36) {                                     \
            uint4 o_;                                                        \
            o_.x = (unsigned int)f2b(acc[0].x) | ((unsigned int)f2b(acc[0].y) << 16); \
            o_.y = (unsigned int)f2b(acc[1].x) | ((unsigned int)f2b(acc[1].y) << 16); \
            o_.z = (unsigned int)f2b(acc[2].x) | ((unsigned int)f2b(acc[2].y) << 16); \
            o_.w = (unsigned int)f2b(acc[3].x) | ((unsigned int)f2b(acc[3].y) << 16); \
            *(uint4*)&sA[(size_t)(rw0 + r_) * F + 8 * lane] = o_;            \
        }                                                                    \
    } while (0)

    // ---- software-pipelined gather: one 8-load batch always in flight ----
    unsigned int offA[8], offB[8];
    uint4 vA[8], vB[8];
    MKOFF(offA, 0); LD8(vA, offA);
    #pragma unroll
    for (int t = 0; t < TOT; t += 2) {
        if (t + 1 < TOT) { MKOFF(offB, t + 1); LD8(vB, offB); }
        CONSUME(vA, t);
        if (t + 2 < TOT) { MKOFF(offA, t + 2); LD8(vA, offA); }
        if (t + 1 < TOT) CONSUME(vB, t + 1);
    }
#undef MKOFF
#undef LD8
#undef CONSUME

    // ---- GEMM phase ----
    int wm = wid & 3, wn = wid >> 2;
    int quad = lane >> 4, r16 = lane & 15;

    floatx4 acc9[9];
    #pragma unroll
    for (int ct = 0; ct < 9; ++ct) acc9[ct] = (floatx4){0.f, 0.f, 0.f, 0.f};

    __syncthreads();   // sA complete + sB[0] staged

    for (int s = 0; s < 9; ++s) {
        if (s < 8 && tid < 128) {
            const unsigned short* srcw = Wp + (size_t)(s + 1) * 4 * F * 8;
            unsigned short* dstb = sB[(s + 1) & 1];
            #pragma unroll
            for (int rr = 0; rr < 9; ++rr)
                gload_lds16(srcw + (rr * 128 + tid) * 8, dstb + (rr * 128 + tid) * 8);
        }
        short8 a0 = *(const short8*)&sA[(wm * 16 + r16) * F + s * 32 + quad * 8];
        const unsigned short* bbp = &sB[s & 1][(quad * F + wn * 144 + r16) * 8];
        #pragma unroll
        for (int ct = 0; ct < 9; ++ct) {
            short8 bf = *(const short8*)(bbp + ct * 128);
            acc9[ct] = __builtin_amdgcn_mfma_f32_16x16x32_bf16(a0, bf, acc9[ct], 0, 0, 0);
        }
        __syncthreads();
    }

    // ---- epilogue ----
    if (LAYER == 1) {
        // prescale rows for layer 2: h1p = relu(acc+b1) * 0.25*dout(row)^-1/2
        int nid = rloc + wm * 16 + quad * 4;          // local content node id (mult of 4)
        int4 dv = *(const int4*)&deg[b * NT + nid];
        float w4[4];
        w4[0] = 0.25f * rsqrtf((float)(dv.x < 1 ? 1 : dv.x));
        w4[1] = 0.25f * rsqrtf((float)(dv.y < 1 ? 1 : dv.y));
        w4[2] = 0.25f * rsqrtf((float)(dv.z < 1 ? 1 : dv.z));
        w4[3] = 0.25f * rsqrtf((float)(dv.w < 1 ? 1 : dv.w));
        #pragma unroll
        for (int ct = 0; ct < 9; ++ct) {
            int col = wn * 144 + ct * 16 + r16;
            float bc = bias[col];
            #pragma unroll
            for (int rg = 0; rg < 4; ++rg) {
                float v = fmaxf(acc9[ct][rg] + bc, 0.f) * w4[rg];
                int grow = row0 + wm * 16 + quad * 4 + rg;
                ((unsigned short*)Cout)[(size_t)grow * F + col] = f2b(v);
            }
        }
    } else {
        #pragma unroll
        for (int ct = 0; ct < 9; ++ct) {
            int col = wn * 144 + ct * 16 + r16;
            float bc = bias[col];
            #pragma unroll
            for (int rg = 0; rg < 4; ++rg) {
                float v = acc9[ct][rg] + bc;
                int grow = row0 + wm * 16 + quad * 4 + rg;
                ((float*)Cout)[(size_t)grow * F + col] = v;
            }
        }
    }
}

extern "C" void kernel_launch(void* const* d_in, const int* in_sizes, int n_in,
                              void* d_out, int out_size, void* d_ws, size_t ws_size,
                              hipStream_t stream) {
    const float* feat_c = (const float*)d_in[0];
    const float* feat_s = (const float*)d_in[1];
    const int*   idx_k1 = (const int*)d_in[2];
    const int*   idx_k2 = (const int*)d_in[3];
    const float* W1     = (const float*)d_in[4];
    const float* b1     = (const float*)d_in[5];
    const float* W2     = (const float*)d_in[6];
    const float* b2     = (const float*)d_in[7];

    char* ws = (char*)d_ws;
    int*            deg  = (int*)ws;                                    // 256 KB
    unsigned short* Wp1  = (unsigned short*)(ws + 262144);
    unsigned short* Wp2  = (unsigned short*)(ws + 262144 + 165888);
    unsigned short* h1b  = (unsigned short*)(ws + 262144 + 2 * 165888); // 18.9 MB (prescaled h1)

    unsigned short* featb = (unsigned short*)d_out;  // 37.75 MB prescaled bf16 table
    float*          out   = (float*)d_out;           // overwrites featb (dead after fused1)

    prep0_kernel<<<P0_DEG + P0_PKW, 1024, 0, stream>>>(
        idx_k1, idx_k2, deg, W1, W2, Wp1, Wp2);

    prep1_kernel<<<P1_BLKS, 1024, 0, stream>>>(deg, feat_c, feat_s, featb);

    fused_kernel<1><<<BM / 64, 512, 0, stream>>>(
        featb, idx_k1, idx_k2, deg, b1, Wp1, b1, (void*)h1b);

    fused_kernel<2><<<BM / 64, 512, 0, stream>>>(
        h1b, idx_k1, idx_k2, deg, b1, Wp2, b2, (void*)out);
}